// Round 1
// baseline (657.065 us; speedup 1.0000x reference)
//
#include <hip/hip_runtime.h>
#include <math.h>

#define EMBED 512
#define HD 256
#define FR 12
#define NV 64
#define TT 16
#define NT_TOK 4096
#define NV_TOK 768

// ---------------- LayerNorm (optional residual add) ----------------
__global__ __launch_bounds__(256) void ln_kernel(
    const float* __restrict__ x, const float* __restrict__ res,
    const float* __restrict__ g, const float* __restrict__ b,
    float* __restrict__ out) {
  int row = blockIdx.x;
  int t = threadIdx.x;
  const float* xr = x + (size_t)row * EMBED;
  float v0 = xr[t];
  float v1 = xr[t + 256];
  if (res != nullptr) {
    const float* rr = res + (size_t)row * EMBED;
    v0 += rr[t];
    v1 += rr[t + 256];
  }
  float s = v0 + v1;
  float s2 = v0 * v0 + v1 * v1;
  #pragma unroll
  for (int off = 32; off > 0; off >>= 1) {
    s += __shfl_down(s, off, 64);
    s2 += __shfl_down(s2, off, 64);
  }
  __shared__ float ss[4], ss2[4];
  __shared__ float mean_s, rstd_s;
  int wid = t >> 6;
  if ((t & 63) == 0) { ss[wid] = s; ss2[wid] = s2; }
  __syncthreads();
  if (t == 0) {
    float a = ss[0] + ss[1] + ss[2] + ss[3];
    float a2 = ss2[0] + ss2[1] + ss2[2] + ss2[3];
    float mean = a * (1.0f / EMBED);
    float var = a2 * (1.0f / EMBED) - mean * mean;
    mean_s = mean;
    rstd_s = rsqrtf(var + 1e-5f);
  }
  __syncthreads();
  float mean = mean_s, rstd = rstd_s;
  float* orow = out + (size_t)row * EMBED;
  orow[t]       = (v0 - mean) * rstd * g[t] + b[t];
  orow[t + 256] = (v1 - mean) * rstd * g[t + 256] + b[t + 256];
}

// ---------------- GEMM: C[M][512] = A[M][512] * W[512][512]^T + bias ----------------
#define BM 64
#define BN 64
#define BK 32
#define LDT 68   // BM+4: keeps float4 rows 16B-aligned (68*4 = 272 = 16*17)

__global__ __launch_bounds__(256) void gemm_bias(
    const float* __restrict__ A, const float* __restrict__ W,
    const float* __restrict__ bias, float* __restrict__ C) {
  __shared__ __align__(16) float As[BK][LDT];  // k-major: As[k][m]
  __shared__ __align__(16) float Ws[BK][LDT];  // k-major: Ws[k][n]
  int tid = threadIdx.x;
  int m0 = blockIdx.x * BM, n0 = blockIdx.y * BN;
  int ty = tid >> 4, tx = tid & 15;
  float acc[4][4] = {};
  // staging: 512 float4 per tile, 2 per thread
  int row0 = tid >> 3;            int kc0 = (tid & 7) << 2;
  int row1 = (tid + 256) >> 3;    int kc1 = kc0;  // (tid+256)&7 == tid&7
  for (int k0 = 0; k0 < EMBED; k0 += BK) {
    float4 va0 = *(const float4*)&A[(size_t)(m0 + row0) * EMBED + k0 + kc0];
    float4 va1 = *(const float4*)&A[(size_t)(m0 + row1) * EMBED + k0 + kc1];
    float4 vw0 = *(const float4*)&W[(size_t)(n0 + row0) * EMBED + k0 + kc0];
    float4 vw1 = *(const float4*)&W[(size_t)(n0 + row1) * EMBED + k0 + kc1];
    __syncthreads();   // previous iteration's compute done
    As[kc0+0][row0]=va0.x; As[kc0+1][row0]=va0.y; As[kc0+2][row0]=va0.z; As[kc0+3][row0]=va0.w;
    As[kc1+0][row1]=va1.x; As[kc1+1][row1]=va1.y; As[kc1+2][row1]=va1.z; As[kc1+3][row1]=va1.w;
    Ws[kc0+0][row0]=vw0.x; Ws[kc0+1][row0]=vw0.y; Ws[kc0+2][row0]=vw0.z; Ws[kc0+3][row0]=vw0.w;
    Ws[kc1+0][row1]=vw1.x; Ws[kc1+1][row1]=vw1.y; Ws[kc1+2][row1]=vw1.z; Ws[kc1+3][row1]=vw1.w;
    __syncthreads();
    #pragma unroll
    for (int kk = 0; kk < BK; ++kk) {
      float4 av = *(const float4*)&As[kk][ty << 2];
      float4 bv = *(const float4*)&Ws[kk][tx << 2];
      float a_[4] = {av.x, av.y, av.z, av.w};
      float b_[4] = {bv.x, bv.y, bv.z, bv.w};
      #pragma unroll
      for (int i = 0; i < 4; ++i)
        #pragma unroll
        for (int j = 0; j < 4; ++j)
          acc[i][j] += a_[i] * b_[j];
    }
  }
  float4 bb = *(const float4*)&bias[n0 + (tx << 2)];
  #pragma unroll
  for (int i = 0; i < 4; ++i) {
    float4 o;
    o.x = acc[i][0] + bb.x; o.y = acc[i][1] + bb.y;
    o.z = acc[i][2] + bb.z; o.w = acc[i][3] + bb.w;
    *(float4*)&C[(size_t)(m0 + (ty << 2) + i) * EMBED + n0 + (tx << 2)] = o;
  }
}

// ---------------- Attention ----------------
// out[i,h,d] = (1/64) * sum_a sum_f softmax_f(q_i . k_{a,f} / 16)[f] * v_{a,f,d}
__device__ __forceinline__ void load16(const float* p, float* dst) {
  float4 a0 = *(const float4*)(p);
  float4 a1 = *(const float4*)(p + 4);
  float4 a2 = *(const float4*)(p + 8);
  float4 a3 = *(const float4*)(p + 12);
  dst[0]=a0.x; dst[1]=a0.y; dst[2]=a0.z;  dst[3]=a0.w;
  dst[4]=a1.x; dst[5]=a1.y; dst[6]=a1.z;  dst[7]=a1.w;
  dst[8]=a2.x; dst[9]=a2.y; dst[10]=a2.z; dst[11]=a2.w;
  dst[12]=a3.x; dst[13]=a3.y; dst[14]=a3.z; dst[15]=a3.w;
}

__global__ __launch_bounds__(256) void attn_kernel(
    const float* __restrict__ Q, const float* __restrict__ K,
    const float* __restrict__ V, float* __restrict__ O) {
  int h = blockIdx.y;
  int i0 = blockIdx.x * TT;
  int tid = threadIdx.x;
  int r = tid >> 4;   // token in tile 0..15
  int c = tid & 15;   // 16-dim chunk 0..15
  __shared__ __align__(16) float Ks[FR][HD];
  __shared__ __align__(16) float Vs[FR][HD];
  __shared__ float part[TT][FR][17];
  __shared__ float wgt[TT][FR];

  float q[16];
  {
    const float* qp = Q + (size_t)(i0 + r) * EMBED + h * HD + (c << 4);
    load16(qp, q);
    #pragma unroll
    for (int j = 0; j < 16; ++j) q[j] *= 0.0625f;  // 1/sqrt(256)
  }
  float acc[16] = {};

  for (int a = 0; a < NV; ++a) {
    __syncthreads();  // protect Ks/Vs from previous iteration's readers
    #pragma unroll
    for (int i = 0; i < 3; ++i) {
      int idx = tid + i * 256;          // 0..767
      int frow = idx >> 6;              // 0..11
      int fcol = (idx & 63) << 2;
      const float* kp = K + (size_t)(a * FR + frow) * EMBED + h * HD + fcol;
      const float* vp = V + (size_t)(a * FR + frow) * EMBED + h * HD + fcol;
      *(float4*)&Ks[frow][fcol] = *(const float4*)kp;
      *(float4*)&Vs[frow][fcol] = *(const float4*)vp;
    }
    __syncthreads();
    #pragma unroll
    for (int f = 0; f < FR; ++f) {
      float kv[16];
      load16(&Ks[f][c << 4], kv);
      float p = 0.f;
      #pragma unroll
      for (int j = 0; j < 16; ++j) p += q[j] * kv[j];
      part[r][f][c] = p;
    }
    __syncthreads();
    if (tid < TT * FR) {
      int r2 = tid / FR, f2 = tid - r2 * FR;
      float s = 0.f;
      #pragma unroll
      for (int c2 = 0; c2 < 16; ++c2) s += part[r2][f2][c2];
      wgt[r2][f2] = s;
    }
    __syncthreads();
    if (tid < TT) {
      float m = wgt[tid][0];
      #pragma unroll
      for (int f = 1; f < FR; ++f) m = fmaxf(m, wgt[tid][f]);
      float s = 0.f;
      #pragma unroll
      for (int f = 0; f < FR; ++f) {
        float e = __expf(wgt[tid][f] - m);
        wgt[tid][f] = e;
        s += e;
      }
      float inv = (1.0f / NV) / s;   // fold mean over a=64 here
      #pragma unroll
      for (int f = 0; f < FR; ++f) wgt[tid][f] *= inv;
    }
    __syncthreads();
    #pragma unroll
    for (int f = 0; f < FR; ++f) {
      float w = wgt[r][f];
      float vv[16];
      load16(&Vs[f][c << 4], vv);
      #pragma unroll
      for (int j = 0; j < 16; ++j) acc[j] += w * vv[j];
    }
  }
  float* op = O + (size_t)(i0 + r) * EMBED + h * HD + (c << 4);
  float4 o0 = {acc[0], acc[1], acc[2], acc[3]};
  float4 o1 = {acc[4], acc[5], acc[6], acc[7]};
  float4 o2 = {acc[8], acc[9], acc[10], acc[11]};
  float4 o3 = {acc[12], acc[13], acc[14], acc[15]};
  *(float4*)(op)      = o0;
  *(float4*)(op + 4)  = o1;
  *(float4*)(op + 8)  = o2;
  *(float4*)(op + 12) = o3;
}

// ---------------- Launch ----------------
extern "C" void kernel_launch(void* const* d_in, const int* in_sizes, int n_in,
                              void* d_out, int out_size, void* d_ws, size_t ws_size,
                              hipStream_t stream) {
  (void)in_sizes; (void)n_in; (void)out_size; (void)ws_size;
  const float* text  = (const float*)d_in[0];
  const float* video = (const float*)d_in[1];
  const float* ln1_g = (const float*)d_in[2];
  const float* ln1_b = (const float*)d_in[3];
  const float* Wq = (const float*)d_in[4];
  const float* bq = (const float*)d_in[5];
  const float* Wk = (const float*)d_in[6];
  const float* bk = (const float*)d_in[7];
  const float* Wv = (const float*)d_in[8];
  const float* bv = (const float*)d_in[9];
  const float* Wo = (const float*)d_in[10];
  const float* bo = (const float*)d_in[11];
  const float* Wl = (const float*)d_in[12];
  const float* bl = (const float*)d_in[13];
  const float* ln2_g = (const float*)d_in[14];
  const float* ln2_b = (const float*)d_in[15];
  const float* ln3_g = (const float*)d_in[16];
  const float* ln3_b = (const float*)d_in[17];
  float* out = (float*)d_out;

  float* ws  = (float*)d_ws;
  float* tn  = ws;                        // [4096*512]  reused as Ob
  float* Qb  = tn + NT_TOK * EMBED;       // [4096*512]  reused as o2
  float* att = Qb + NT_TOK * EMBED;       // [4096*512]  reused as linb
  float* vn  = att + NT_TOK * EMBED;      // [768*512]
  float* Kb  = vn + NV_TOK * EMBED;       // [768*512]
  float* Vb  = Kb + NV_TOK * EMBED;       // [768*512]

  ln_kernel<<<NT_TOK, 256, 0, stream>>>(text, nullptr, ln1_g, ln1_b, tn);
  ln_kernel<<<NV_TOK, 256, 0, stream>>>(video, nullptr, ln1_g, ln1_b, vn);

  gemm_bias<<<dim3(NT_TOK / BM, EMBED / BN), 256, 0, stream>>>(tn, Wq, bq, Qb);
  gemm_bias<<<dim3(NV_TOK / BM, EMBED / BN), 256, 0, stream>>>(vn, Wk, bk, Kb);
  gemm_bias<<<dim3(NV_TOK / BM, EMBED / BN), 256, 0, stream>>>(vn, Wv, bv, Vb);

  attn_kernel<<<dim3(NT_TOK / TT, 2), 256, 0, stream>>>(Qb, Kb, Vb, att);

  float* Ob = tn;
  gemm_bias<<<dim3(NT_TOK / BM, EMBED / BN), 256, 0, stream>>>(att, Wo, bo, Ob);
  float* o2 = Qb;
  ln_kernel<<<NT_TOK, 256, 0, stream>>>(Ob, nullptr, ln2_g, ln2_b, o2);
  float* linb = att;
  gemm_bias<<<dim3(NT_TOK / BM, EMBED / BN), 256, 0, stream>>>(o2, Wl, bl, linb);
  ln_kernel<<<NT_TOK, 256, 0, stream>>>(o2, linb, ln3_g, ln3_b, out);
}

// Round 2
// 183.931 us; speedup vs baseline: 3.5724x; 3.5724x over previous
//
#include <hip/hip_runtime.h>
#include <math.h>

#define EMBED 512
#define HD 256
#define FR 12
#define NV 64
#define NT_TOK 4096
#define NV_TOK 768

typedef __attribute__((ext_vector_type(8))) short short8;
typedef __attribute__((ext_vector_type(4))) float f32x4;

__device__ __forceinline__ unsigned short f2bf(float f) {
  unsigned int u = __float_as_uint(f);
  u += 0x7FFFu + ((u >> 16) & 1u);   // RNE
  return (unsigned short)(u >> 16);
}
__device__ __forceinline__ float bf2f(unsigned short h) {
  return __uint_as_float(((unsigned int)h) << 16);
}
__device__ __forceinline__ void async_cp16(void* lds, const void* g) {
  __builtin_amdgcn_global_load_lds(
      (const __attribute__((address_space(1))) void*)g,
      (__attribute__((address_space(3))) void*)lds, 16, 0, 0);
}

// ---------------- LayerNorm (optional residual, fp32 and/or bf16 out) -------
__global__ __launch_bounds__(256) void ln_kernel(
    const float* __restrict__ x, const float* __restrict__ res,
    const float* __restrict__ g, const float* __restrict__ b,
    float* __restrict__ outf, unsigned short* __restrict__ outb) {
  int row = blockIdx.x;
  int t = threadIdx.x;
  const float* xr = x + (size_t)row * EMBED;
  float v0 = xr[t];
  float v1 = xr[t + 256];
  if (res != nullptr) {
    const float* rr = res + (size_t)row * EMBED;
    v0 += rr[t];
    v1 += rr[t + 256];
  }
  float s = v0 + v1;
  float s2 = v0 * v0 + v1 * v1;
  #pragma unroll
  for (int off = 32; off > 0; off >>= 1) {
    s += __shfl_down(s, off, 64);
    s2 += __shfl_down(s2, off, 64);
  }
  __shared__ float ss[4], ss2[4];
  __shared__ float mean_s, rstd_s;
  int wid = t >> 6;
  if ((t & 63) == 0) { ss[wid] = s; ss2[wid] = s2; }
  __syncthreads();
  if (t == 0) {
    float a = ss[0] + ss[1] + ss[2] + ss[3];
    float a2 = ss2[0] + ss2[1] + ss2[2] + ss2[3];
    float mean = a * (1.0f / EMBED);
    float var = a2 * (1.0f / EMBED) - mean * mean;
    mean_s = mean;
    rstd_s = rsqrtf(var + 1e-5f);
  }
  __syncthreads();
  float mean = mean_s, rstd = rstd_s;
  float y0 = (v0 - mean) * rstd * g[t] + b[t];
  float y1 = (v1 - mean) * rstd * g[t + 256] + b[t + 256];
  if (outf != nullptr) {
    float* orow = outf + (size_t)row * EMBED;
    orow[t] = y0;
    orow[t + 256] = y1;
  }
  if (outb != nullptr) {
    unsigned short* orow = outb + (size_t)row * EMBED;
    orow[t] = f2bf(y0);
    orow[t + 256] = f2bf(y1);
  }
}

// ---------------- bf16 MFMA GEMM: C = A @ B^T (+bias) ----------------------
// A: [M][lda] bf16 (rows m, k contiguous), B: [N][ldb] bf16 (rows n, k contig)
// 64x64 tile, BK=64, 4 waves each computing a 32x32 quadrant via 2x2 of
// 16x16x32 MFMA. LDS tiles XOR-swizzled (chunk ^ row&7) so global_load_lds's
// forced lane-linear layout still yields conflict-minimal ds_read_b128.
template <bool OUT_BF, bool BIAS>
__global__ __launch_bounds__(256) void gemm_mfma(
    const unsigned short* __restrict__ A, int lda, long AzS,
    const unsigned short* __restrict__ B, int ldb, long BzS,
    const float* __restrict__ bias, void* __restrict__ Cv, int ldc, long CzS,
    int K) {
  __shared__ __align__(16) unsigned short As[64 * 64];
  __shared__ __align__(16) unsigned short Bs[64 * 64];
  int tid = threadIdx.x;
  int w = tid >> 6, lane = tid & 63;
  int m0 = blockIdx.x * 64, n0 = blockIdx.y * 64;
  const unsigned short* Ab = A + (size_t)blockIdx.z * AzS;
  const unsigned short* Bb = B + (size_t)blockIdx.z * BzS;
  int wm = (w >> 1) * 32, wn = (w & 1) * 32;
  int lr = lane & 15, quad = lane >> 4;

  // staging indices: wave w loads rows [w*16, w*16+16), 2 issues of 64 lanes
  int s0 = lane, s1 = 64 + lane;
  int row0 = (w << 4) + (s0 >> 3), c0l = s0 & 7, c0g = c0l ^ (row0 & 7);
  int row1 = (w << 4) + (s1 >> 3), c1l = s1 & 7, c1g = c1l ^ (row1 & 7);

  f32x4 acc[2][2] = {};
  for (int k0 = 0; k0 < K; k0 += 64) {
    __syncthreads();  // previous iteration's ds_reads done
    async_cp16(&As[row0 * 64 + c0l * 8], Ab + (size_t)(m0 + row0) * lda + k0 + c0g * 8);
    async_cp16(&As[row1 * 64 + c1l * 8], Ab + (size_t)(m0 + row1) * lda + k0 + c1g * 8);
    async_cp16(&Bs[row0 * 64 + c0l * 8], Bb + (size_t)(n0 + row0) * ldb + k0 + c0g * 8);
    async_cp16(&Bs[row1 * 64 + c1l * 8], Bb + (size_t)(n0 + row1) * ldb + k0 + c1g * 8);
    __syncthreads();  // drains vmcnt (global_load_lds) per barrier semantics
    #pragma unroll
    for (int kk = 0; kk < 2; ++kk) {
      int sw = ((kk * 4 + quad) ^ (lr & 7)) * 8;
      short8 a0 = *(const short8*)&As[(wm + lr) * 64 + sw];
      short8 a1 = *(const short8*)&As[(wm + 16 + lr) * 64 + sw];
      short8 b0 = *(const short8*)&Bs[(wn + lr) * 64 + sw];
      short8 b1 = *(const short8*)&Bs[(wn + 16 + lr) * 64 + sw];
      acc[0][0] = __builtin_amdgcn_mfma_f32_16x16x32_bf16(a0, b0, acc[0][0], 0, 0, 0);
      acc[0][1] = __builtin_amdgcn_mfma_f32_16x16x32_bf16(a0, b1, acc[0][1], 0, 0, 0);
      acc[1][0] = __builtin_amdgcn_mfma_f32_16x16x32_bf16(a1, b0, acc[1][0], 0, 0, 0);
      acc[1][1] = __builtin_amdgcn_mfma_f32_16x16x32_bf16(a1, b1, acc[1][1], 0, 0, 0);
    }
  }
  // epilogue: C/D layout col=lane&15, row=quad*4+reg (m89/m91-verified)
  long cz = (long)blockIdx.z * CzS;
  #pragma unroll
  for (int im = 0; im < 2; ++im) {
    #pragma unroll
    for (int in = 0; in < 2; ++in) {
      int col = n0 + wn + in * 16 + lr;
      float bv = BIAS ? bias[col] : 0.0f;
      int rbase = m0 + wm + im * 16 + quad * 4;
      #pragma unroll
      for (int r = 0; r < 4; ++r) {
        float v = acc[im][in][r] + bv;
        if (OUT_BF)
          ((unsigned short*)Cv)[cz + (size_t)(rbase + r) * ldc + col] = f2bf(v);
        else
          ((float*)Cv)[cz + (size_t)(rbase + r) * ldc + col] = v;
      }
    }
  }
}

// ---------------- fp32 -> bf16 weight conversion (5 x 512x512) -------------
__global__ __launch_bounds__(256) void cvt5_kernel(
    const float* __restrict__ w0, const float* __restrict__ w1,
    const float* __restrict__ w2, const float* __restrict__ w3,
    const float* __restrict__ w4, unsigned short* __restrict__ out) {
  int i = blockIdx.x * 256 + threadIdx.x;  // one float4 each; 5*65536 total
  const float* srcs[5] = {w0, w1, w2, w3, w4};
  const float* src = srcs[i >> 16];
  float4 v = ((const float4*)src)[i & 65535];
  uint2 o;
  o.x = (unsigned)f2bf(v.x) | ((unsigned)f2bf(v.y) << 16);
  o.y = (unsigned)f2bf(v.z) | ((unsigned)f2bf(v.w) << 16);
  ((uint2*)out)[i] = o;
}

// ---------------- in-place group softmax over 12 frames --------------------
// S: bf16 [2][4096][768]; each thread owns one 12-group. Folds 1/16 logit
// scale and 1/64 batch-mean into the weights.
__global__ __launch_bounds__(256) void softmax12_kernel(unsigned short* __restrict__ S) {
  int gi = blockIdx.x * 256 + threadIdx.x;  // 524288 groups
  uint2* p = (uint2*)(S + (size_t)gi * 12);
  uint2 u0 = p[0], u1 = p[1], u2 = p[2];
  float v[12];
  v[0] = bf2f(u0.x & 0xffff); v[1] = bf2f(u0.x >> 16);
  v[2] = bf2f(u0.y & 0xffff); v[3] = bf2f(u0.y >> 16);
  v[4] = bf2f(u1.x & 0xffff); v[5] = bf2f(u1.x >> 16);
  v[6] = bf2f(u1.y & 0xffff); v[7] = bf2f(u1.y >> 16);
  v[8] = bf2f(u2.x & 0xffff); v[9] = bf2f(u2.x >> 16);
  v[10] = bf2f(u2.y & 0xffff); v[11] = bf2f(u2.y >> 16);
  float m = -1e30f;
  #pragma unroll
  for (int f = 0; f < FR; ++f) { v[f] *= 0.0625f; m = fmaxf(m, v[f]); }
  float s = 0.f;
  #pragma unroll
  for (int f = 0; f < FR; ++f) { v[f] = __expf(v[f] - m); s += v[f]; }
  float inv = (1.0f / NV) / s;
  unsigned short w[12];
  #pragma unroll
  for (int f = 0; f < FR; ++f) w[f] = f2bf(v[f] * inv);
  uint2 o0, o1, o2;
  o0.x = (unsigned)w[0] | ((unsigned)w[1] << 16);
  o0.y = (unsigned)w[2] | ((unsigned)w[3] << 16);
  o1.x = (unsigned)w[4] | ((unsigned)w[5] << 16);
  o1.y = (unsigned)w[6] | ((unsigned)w[7] << 16);
  o2.x = (unsigned)w[8] | ((unsigned)w[9] << 16);
  o2.y = (unsigned)w[10] | ((unsigned)w[11] << 16);
  p[0] = o0; p[1] = o1; p[2] = o2;
}

// ---------------- bf16 transpose: V[768][512] -> Vt[512][768] --------------
__global__ __launch_bounds__(256) void transpose_kernel(
    const unsigned short* __restrict__ V, unsigned short* __restrict__ Vt) {
  __shared__ unsigned short tile[32][34];
  int x = threadIdx.x & 31, y = threadIdx.x >> 5;  // y 0..7
  int t0 = blockIdx.x * 32, n0 = blockIdx.y * 32;
  #pragma unroll
  for (int i = 0; i < 4; ++i)
    tile[y + i * 8][x] = V[(size_t)(t0 + y + i * 8) * EMBED + n0 + x];
  __syncthreads();
  #pragma unroll
  for (int i = 0; i < 4; ++i)
    Vt[(size_t)(n0 + y + i * 8) * NV_TOK + t0 + x] = tile[x][y + i * 8];
}

// ---------------- Launch ----------------
extern "C" void kernel_launch(void* const* d_in, const int* in_sizes, int n_in,
                              void* d_out, int out_size, void* d_ws, size_t ws_size,
                              hipStream_t stream) {
  (void)in_sizes; (void)n_in; (void)out_size; (void)ws_size;
  const float* text  = (const float*)d_in[0];
  const float* video = (const float*)d_in[1];
  const float* ln1_g = (const float*)d_in[2];
  const float* ln1_b = (const float*)d_in[3];
  const float* Wq = (const float*)d_in[4];
  const float* bq = (const float*)d_in[5];
  const float* Wk = (const float*)d_in[6];
  const float* bk = (const float*)d_in[7];
  const float* Wv = (const float*)d_in[8];
  const float* bv = (const float*)d_in[9];
  const float* Wo = (const float*)d_in[10];
  const float* bo = (const float*)d_in[11];
  const float* Wl = (const float*)d_in[12];
  const float* bl = (const float*)d_in[13];
  const float* ln2_g = (const float*)d_in[14];
  const float* ln2_b = (const float*)d_in[15];
  const float* ln3_g = (const float*)d_in[16];
  const float* ln3_b = (const float*)d_in[17];
  float* out = (float*)d_out;

  // ---- workspace layout (29,360,128 B total; aliased phase-by-phase) ----
  char* base = (char*)d_ws;
  unsigned short* Wbf   = (unsigned short*)base;          // 5 x 262144 bf16
  unsigned short* Wq_bf = Wbf + 0 * 262144;
  unsigned short* Wk_bf = Wbf + 1 * 262144;
  unsigned short* Wv_bf = Wbf + 2 * 262144;
  unsigned short* Wo_bf = Wbf + 3 * 262144;
  unsigned short* Wl_bf = Wbf + 4 * 262144;
  unsigned short* Vt    = (unsigned short*)(base + 2621440);  // [512][768]
  char* big = base + 3407872;
  unsigned short* Q_bf   = (unsigned short*)(big + 0);         // 4096x512
  unsigned short* K_bf   = (unsigned short*)(big + 4194304);   // 768x512
  unsigned short* S      = (unsigned short*)(big + 4980736);   // 2x4096x768
  unsigned short* tn_bf  = (unsigned short*)(big + 17563648);  // 4096x512
  unsigned short* vn_bf  = (unsigned short*)(big + 21757952);  // 768x512
  unsigned short* V_bf   = (unsigned short*)(big + 22544384);  // 768x512
  unsigned short* att_bf = (unsigned short*)(big + 17563648);  // over tn (dead)
  float*          Ob     = (float*)(big + 4980736);            // over S (dead)
  float*          o2f    = (float*)(big + 13369344);
  unsigned short* o2_bf  = (unsigned short*)(big + 21757952);  // over vn/V (dead)
  float*          lin    = (float*)(big + 0);                  // over Q/K/Ob (dead)

  cvt5_kernel<<<1280, 256, 0, stream>>>(Wq, Wk, Wv, Wo, Wl, Wbf);
  ln_kernel<<<NT_TOK, 256, 0, stream>>>(text, nullptr, ln1_g, ln1_b, nullptr, tn_bf);
  ln_kernel<<<NV_TOK, 256, 0, stream>>>(video, nullptr, ln1_g, ln1_b, nullptr, vn_bf);

  gemm_mfma<true, true><<<dim3(64, 8, 1), 256, 0, stream>>>(
      tn_bf, EMBED, 0, Wq_bf, EMBED, 0, bq, Q_bf, EMBED, 0, EMBED);
  gemm_mfma<true, true><<<dim3(12, 8, 1), 256, 0, stream>>>(
      vn_bf, EMBED, 0, Wk_bf, EMBED, 0, bk, K_bf, EMBED, 0, EMBED);
  gemm_mfma<true, true><<<dim3(12, 8, 1), 256, 0, stream>>>(
      vn_bf, EMBED, 0, Wv_bf, EMBED, 0, bv, V_bf, EMBED, 0, EMBED);
  transpose_kernel<<<dim3(24, 16), 256, 0, stream>>>(V_bf, Vt);

  // S[h] = Q_h @ K_h^T  (logits, bf16 out; scale folded into softmax)
  gemm_mfma<true, false><<<dim3(64, 12, 2), 256, 0, stream>>>(
      Q_bf, EMBED, HD, K_bf, EMBED, HD, nullptr, S, NV_TOK, (long)NT_TOK * NV_TOK, HD);
  softmax12_kernel<<<2048, 256, 0, stream>>>(S);
  // att[:, h*256+d] = P[h] @ Vt[h]^T
  gemm_mfma<true, false><<<dim3(64, 4, 2), 256, 0, stream>>>(
      S, NV_TOK, (long)NT_TOK * NV_TOK, Vt, NV_TOK, (long)HD * NV_TOK, nullptr,
      att_bf, EMBED, HD, NV_TOK);

  gemm_mfma<false, true><<<dim3(64, 8, 1), 256, 0, stream>>>(
      att_bf, EMBED, 0, Wo_bf, EMBED, 0, bo, Ob, EMBED, 0, EMBED);
  ln_kernel<<<NT_TOK, 256, 0, stream>>>(Ob, nullptr, ln2_g, ln2_b, o2f, o2_bf);
  gemm_mfma<false, true><<<dim3(64, 8, 1), 256, 0, stream>>>(
      o2_bf, EMBED, 0, Wl_bf, EMBED, 0, bl, lin, EMBED, 0, EMBED);
  ln_kernel<<<NT_TOK, 256, 0, stream>>>(o2f, lin, ln3_g, ln3_b, out, nullptr);
}

// Round 3
// 176.205 us; speedup vs baseline: 3.7290x; 1.0438x over previous
//
#include <hip/hip_runtime.h>
#include <math.h>

#define EMBED 512
#define HD 256
#define FR 12
#define NV 64
#define NT_TOK 4096
#define NV_TOK 768

typedef __attribute__((ext_vector_type(8))) short short8;
typedef __attribute__((ext_vector_type(4))) float f32x4;

__device__ __forceinline__ unsigned int f2bf(float f) {
  unsigned int u = __float_as_uint(f);
  u += 0x7FFFu + ((u >> 16) & 1u);   // RNE
  return u >> 16;
}
__device__ __forceinline__ float bf2f(unsigned int h) {
  return __uint_as_float(h << 16);
}
__device__ __forceinline__ void async_cp16(void* lds, const void* g) {
  __builtin_amdgcn_global_load_lds(
      (const __attribute__((address_space(1))) void*)g,
      (__attribute__((address_space(3))) void*)lds, 16, 0, 0);
}

// ================= GEMM core: 128x64 C-tile, BK=64, 4 waves of 64x32 =======
// A: [M][lda] bf16 rows-m k-contig; B: [N][ldb] bf16 rows-n k-contig.
// LDS XOR-swizzled (chunk ^ row&7); global_load_lds dest is lane-linear.
// acc[i][j]: i = 4 m-frags (16 rows each), j = 2 n-frags.
__device__ __forceinline__ void gemm_core(
    const unsigned short* __restrict__ Ab, int lda,
    const unsigned short* __restrict__ Bb, int ldb,
    int m0, int n0, int K,
    unsigned short* As, unsigned short* Bs, f32x4 acc[4][2]) {
  int tid = threadIdx.x;
  int w = tid >> 6, lane = tid & 63;
  int lr = lane & 15, quad = lane >> 4;
  int wm = (w >> 1) * 64, wn = (w & 1) * 32;
  int rowA[4], cgA[4], rowB[2], cgB[2];
  #pragma unroll
  for (int i = 0; i < 4; ++i) {
    int s = tid + i * 256;
    rowA[i] = s >> 3;
    cgA[i] = (s & 7) ^ (rowA[i] & 7);
  }
  #pragma unroll
  for (int i = 0; i < 2; ++i) {
    int s = tid + i * 256;
    rowB[i] = s >> 3;
    cgB[i] = (s & 7) ^ (rowB[i] & 7);
  }
  for (int k0 = 0; k0 < K; k0 += 64) {
    __syncthreads();  // previous iteration's ds_reads done
    #pragma unroll
    for (int i = 0; i < 4; ++i)
      async_cp16(&As[(tid + i * 256) * 8],
                 Ab + (size_t)(m0 + rowA[i]) * lda + k0 + cgA[i] * 8);
    #pragma unroll
    for (int i = 0; i < 2; ++i)
      async_cp16(&Bs[(tid + i * 256) * 8],
                 Bb + (size_t)(n0 + rowB[i]) * ldb + k0 + cgB[i] * 8);
    __syncthreads();  // barrier drains vmcnt (global_load_lds complete)
    #pragma unroll
    for (int kk = 0; kk < 2; ++kk) {
      int sw = ((kk * 4 + quad) ^ (lr & 7)) * 8;
      short8 b0 = *(const short8*)&Bs[(wn + lr) * 64 + sw];
      short8 b1 = *(const short8*)&Bs[(wn + 16 + lr) * 64 + sw];
      #pragma unroll
      for (int i = 0; i < 4; ++i) {
        short8 a = *(const short8*)&As[(wm + i * 16 + lr) * 64 + sw];
        acc[i][0] = __builtin_amdgcn_mfma_f32_16x16x32_bf16(a, b0, acc[i][0], 0, 0, 0);
        acc[i][1] = __builtin_amdgcn_mfma_f32_16x16x32_bf16(a, b1, acc[i][1], 0, 0, 0);
      }
    }
  }
}

// ================= generic GEMM kernel (S / PV / O / L) ====================
template <bool OUT_BF, bool BIAS>
__global__ __launch_bounds__(256) void gemm128(
    const unsigned short* __restrict__ A, int lda, long AzS,
    const unsigned short* __restrict__ B, int ldb, long BzS,
    const float* __restrict__ bias, void* __restrict__ Cv, int ldc, long CzS,
    int K) {
  __shared__ __align__(16) unsigned short As[128 * 64];
  __shared__ __align__(16) unsigned short Bs[64 * 64];
  f32x4 acc[4][2] = {};
  const unsigned short* Ab = A + (size_t)blockIdx.z * AzS;
  const unsigned short* Bb = B + (size_t)blockIdx.z * BzS;
  int m0 = blockIdx.x * 128, n0 = blockIdx.y * 64;
  gemm_core(Ab, lda, Bb, ldb, m0, n0, K, As, Bs, acc);
  int w = threadIdx.x >> 6, lane = threadIdx.x & 63;
  int lr = lane & 15, quad = lane >> 4;
  int wm = (w >> 1) * 64, wn = (w & 1) * 32;
  long cz = (long)blockIdx.z * CzS;
  #pragma unroll
  for (int j = 0; j < 2; ++j) {
    int col = n0 + wn + j * 16 + lr;
    float bv = BIAS ? bias[col] : 0.0f;
    #pragma unroll
    for (int i = 0; i < 4; ++i) {
      int rbase = m0 + wm + i * 16 + quad * 4;
      #pragma unroll
      for (int r = 0; r < 4; ++r) {
        float v = acc[i][j][r] + bv;
        if (OUT_BF)
          ((unsigned short*)Cv)[cz + (size_t)(rbase + r) * ldc + col] =
              (unsigned short)f2bf(v);
        else
          ((float*)Cv)[cz + (size_t)(rbase + r) * ldc + col] = v;
      }
    }
  }
}

// ================= fused Q/K/V projection (+ direct-transposed V) ==========
__global__ __launch_bounds__(256) void qkv_kernel(
    const unsigned short* __restrict__ tn, const unsigned short* __restrict__ vn,
    const unsigned short* __restrict__ Wq, const unsigned short* __restrict__ Wk,
    const unsigned short* __restrict__ Wv,
    const float* __restrict__ bq, const float* __restrict__ bk,
    const float* __restrict__ bv,
    unsigned short* __restrict__ Q, unsigned short* __restrict__ Kout,
    unsigned short* __restrict__ Vt) {
  __shared__ __align__(16) unsigned short As[128 * 64];
  __shared__ __align__(16) unsigned short Bs[64 * 64];
  int bid = blockIdx.x;
  const unsigned short *Ap, *Bp;
  const float* bias;
  unsigned short* outp = nullptr;
  int m0, n0, mode;
  if (bid < 256) {            // Q: 32x8 blocks
    Ap = tn; Bp = Wq; bias = bq; outp = Q;
    m0 = (bid >> 3) * 128; n0 = (bid & 7) * 64; mode = 0;
  } else if (bid < 304) {     // K: 6x8 blocks
    int i = bid - 256;
    Ap = vn; Bp = Wk; bias = bk; outp = Kout;
    m0 = (i >> 3) * 128; n0 = (i & 7) * 64; mode = 0;
  } else {                    // V -> Vt: 6x8 blocks
    int i = bid - 304;
    Ap = vn; Bp = Wv; bias = bv;
    m0 = (i >> 3) * 128; n0 = (i & 7) * 64; mode = 1;
  }
  f32x4 acc[4][2] = {};
  gemm_core(Ap, EMBED, Bp, EMBED, m0, n0, EMBED, As, Bs, acc);
  int w = threadIdx.x >> 6, lane = threadIdx.x & 63;
  int lr = lane & 15, quad = lane >> 4;
  int wm = (w >> 1) * 64, wn = (w & 1) * 32;
  #pragma unroll
  for (int j = 0; j < 2; ++j) {
    int col = n0 + wn + j * 16 + lr;
    float bvv = bias[col];
    #pragma unroll
    for (int i = 0; i < 4; ++i) {
      int rbase = m0 + wm + i * 16 + quad * 4;
      if (mode == 0) {
        #pragma unroll
        for (int r = 0; r < 4; ++r)
          outp[(size_t)(rbase + r) * EMBED + col] =
              (unsigned short)f2bf(acc[i][j][r] + bvv);
      } else {
        ushort4 pk;
        pk.x = (unsigned short)f2bf(acc[i][j][0] + bvv);
        pk.y = (unsigned short)f2bf(acc[i][j][1] + bvv);
        pk.z = (unsigned short)f2bf(acc[i][j][2] + bvv);
        pk.w = (unsigned short)f2bf(acc[i][j][3] + bvv);
        *(ushort4*)&Vt[(size_t)col * NV_TOK + rbase] = pk;  // Vt[d][t]
      }
    }
  }
}

// ================= LayerNorm row helper ====================================
__device__ __forceinline__ void ln_row(
    const float* __restrict__ xr, const float* __restrict__ rr,
    const float* __restrict__ g, const float* __restrict__ b,
    float* __restrict__ outf, unsigned short* __restrict__ outb) {
  int t = threadIdx.x;
  float v0 = xr[t], v1 = xr[t + 256];
  if (rr != nullptr) { v0 += rr[t]; v1 += rr[t + 256]; }
  float s = v0 + v1;
  float s2 = v0 * v0 + v1 * v1;
  #pragma unroll
  for (int off = 32; off > 0; off >>= 1) {
    s += __shfl_down(s, off, 64);
    s2 += __shfl_down(s2, off, 64);
  }
  __shared__ float ss[4], ss2[4];
  __shared__ float mean_s, rstd_s;
  int wid = t >> 6;
  if ((t & 63) == 0) { ss[wid] = s; ss2[wid] = s2; }
  __syncthreads();
  if (t == 0) {
    float a = ss[0] + ss[1] + ss[2] + ss[3];
    float a2 = ss2[0] + ss2[1] + ss2[2] + ss2[3];
    float mean = a * (1.0f / EMBED);
    float var = a2 * (1.0f / EMBED) - mean * mean;
    mean_s = mean;
    rstd_s = rsqrtf(var + 1e-5f);
  }
  __syncthreads();
  float mean = mean_s, rstd = rstd_s;
  float y0 = (v0 - mean) * rstd * g[t] + b[t];
  float y1 = (v1 - mean) * rstd * g[t + 256] + b[t + 256];
  if (outf != nullptr) { outf[t] = y0; outf[t + 256] = y1; }
  if (outb != nullptr) {
    outb[t] = (unsigned short)f2bf(y0);
    outb[t + 256] = (unsigned short)f2bf(y1);
  }
}

__global__ __launch_bounds__(256) void ln_kernel(
    const float* __restrict__ x, const float* __restrict__ res,
    const float* __restrict__ g, const float* __restrict__ b,
    float* __restrict__ outf, unsigned short* __restrict__ outb) {
  size_t row = blockIdx.x;
  ln_row(x + row * EMBED, res ? res + row * EMBED : nullptr, g, b,
         outf ? outf + row * EMBED : nullptr,
         outb ? outb + row * EMBED : nullptr);
}

// ========= prep: weight fp32->bf16 (5x512x512) + LN1 on text & video =======
__global__ __launch_bounds__(256) void prep_kernel(
    const float* __restrict__ text, const float* __restrict__ video,
    const float* __restrict__ g, const float* __restrict__ b,
    const float* __restrict__ Wq, const float* __restrict__ Wk,
    const float* __restrict__ Wv, const float* __restrict__ Wo,
    const float* __restrict__ Wl, unsigned short* __restrict__ Wbf,
    unsigned short* __restrict__ tn, unsigned short* __restrict__ vn) {
  int bid = blockIdx.x;
  if (bid < 1280) {  // weight convert: one float4 per thread
    int i = bid * 256 + threadIdx.x;
    const float* srcs[5] = {Wq, Wk, Wv, Wo, Wl};
    const float* src = srcs[i >> 16];
    float4 v = ((const float4*)src)[i & 65535];
    uint2 o;
    o.x = f2bf(v.x) | (f2bf(v.y) << 16);
    o.y = f2bf(v.z) | (f2bf(v.w) << 16);
    ((uint2*)Wbf)[i] = o;
    return;
  }
  if (bid < 1280 + NT_TOK) {
    size_t row = bid - 1280;
    ln_row(text + row * EMBED, nullptr, g, b, nullptr, tn + row * EMBED);
  } else {
    size_t row = bid - (1280 + NT_TOK);
    ln_row(video + row * EMBED, nullptr, g, b, nullptr, vn + row * EMBED);
  }
}

// ========= in-place group softmax over 12 frames (folds 1/16 and 1/64) =====
__global__ __launch_bounds__(256) void softmax12_kernel(unsigned short* __restrict__ S) {
  int gi = blockIdx.x * 256 + threadIdx.x;  // 524288 groups of 12
  uint2* p = (uint2*)(S + (size_t)gi * 12);
  uint2 u0 = p[0], u1 = p[1], u2 = p[2];
  float v[12];
  v[0] = bf2f(u0.x & 0xffff); v[1] = bf2f(u0.x >> 16);
  v[2] = bf2f(u0.y & 0xffff); v[3] = bf2f(u0.y >> 16);
  v[4] = bf2f(u1.x & 0xffff); v[5] = bf2f(u1.x >> 16);
  v[6] = bf2f(u1.y & 0xffff); v[7] = bf2f(u1.y >> 16);
  v[8] = bf2f(u2.x & 0xffff); v[9] = bf2f(u2.x >> 16);
  v[10] = bf2f(u2.y & 0xffff); v[11] = bf2f(u2.y >> 16);
  float m = -1e30f;
  #pragma unroll
  for (int f = 0; f < FR; ++f) { v[f] *= 0.0625f; m = fmaxf(m, v[f]); }
  float s = 0.f;
  #pragma unroll
  for (int f = 0; f < FR; ++f) { v[f] = __expf(v[f] - m); s += v[f]; }
  float inv = (1.0f / NV) / s;
  unsigned int w[12];
  #pragma unroll
  for (int f = 0; f < FR; ++f) w[f] = f2bf(v[f] * inv);
  uint2 o0, o1, o2;
  o0.x = w[0] | (w[1] << 16);  o0.y = w[2] | (w[3] << 16);
  o1.x = w[4] | (w[5] << 16);  o1.y = w[6] | (w[7] << 16);
  o2.x = w[8] | (w[9] << 16);  o2.y = w[10] | (w[11] << 16);
  p[0] = o0; p[1] = o1; p[2] = o2;
}

// ================= Launch ==================================================
extern "C" void kernel_launch(void* const* d_in, const int* in_sizes, int n_in,
                              void* d_out, int out_size, void* d_ws, size_t ws_size,
                              hipStream_t stream) {
  (void)in_sizes; (void)n_in; (void)out_size; (void)ws_size;
  const float* text  = (const float*)d_in[0];
  const float* video = (const float*)d_in[1];
  const float* ln1_g = (const float*)d_in[2];
  const float* ln1_b = (const float*)d_in[3];
  const float* Wq = (const float*)d_in[4];
  const float* bq = (const float*)d_in[5];
  const float* Wk = (const float*)d_in[6];
  const float* bk = (const float*)d_in[7];
  const float* Wv = (const float*)d_in[8];
  const float* bv = (const float*)d_in[9];
  const float* Wo = (const float*)d_in[10];
  const float* bo = (const float*)d_in[11];
  const float* Wl = (const float*)d_in[12];
  const float* bl = (const float*)d_in[13];
  const float* ln2_g = (const float*)d_in[14];
  const float* ln2_b = (const float*)d_in[15];
  const float* ln3_g = (const float*)d_in[16];
  const float* ln3_b = (const float*)d_in[17];
  float* out = (float*)d_out;

  // ---- workspace layout (29.36 MB; aliased phase-by-phase) ----
  char* base = (char*)d_ws;
  unsigned short* Wbf   = (unsigned short*)base;              // 5 x 262144 bf16
  unsigned short* Wq_bf = Wbf + 0 * 262144;
  unsigned short* Wk_bf = Wbf + 1 * 262144;
  unsigned short* Wv_bf = Wbf + 2 * 262144;
  unsigned short* Wo_bf = Wbf + 3 * 262144;
  unsigned short* Wl_bf = Wbf + 4 * 262144;
  unsigned short* Vt    = (unsigned short*)(base + 2621440);  // [512][768]
  char* big = base + 3407872;
  unsigned short* Q_bf   = (unsigned short*)(big + 0);         // 4096x512
  unsigned short* K_bf   = (unsigned short*)(big + 4194304);   // 768x512
  unsigned short* S      = (unsigned short*)(big + 4980736);   // 2x4096x768
  unsigned short* tn_bf  = (unsigned short*)(big + 17563648);  // 4096x512
  unsigned short* vn_bf  = (unsigned short*)(big + 21757952);  // 768x512
  unsigned short* att_bf = (unsigned short*)(big + 17563648);  // over tn (dead)
  float*          Ob     = (float*)(big + 4980736);            // over S (dead)
  float*          o2f    = (float*)(big + 13369344);           // over S tail
  unsigned short* o2_bf  = (unsigned short*)(big + 21757952);  // over vn (dead)
  float*          lin    = (float*)(big + 0);                  // over Q/K (dead)

  prep_kernel<<<1280 + NT_TOK + NV_TOK, 256, 0, stream>>>(
      text, video, ln1_g, ln1_b, Wq, Wk, Wv, Wo, Wl, Wbf, tn_bf, vn_bf);

  qkv_kernel<<<352, 256, 0, stream>>>(tn_bf, vn_bf, Wq_bf, Wk_bf, Wv_bf,
                                      bq, bk, bv, Q_bf, K_bf, Vt);

  // S[h] = Q_h @ K_h^T  (logits; scale folded into softmax)
  gemm128<true, false><<<dim3(32, 12, 2), 256, 0, stream>>>(
      Q_bf, EMBED, HD, K_bf, EMBED, HD, nullptr, S, NV_TOK,
      (long)NT_TOK * NV_TOK, HD);
  softmax12_kernel<<<2048, 256, 0, stream>>>(S);
  // att[:, h*256+d] = P[h] @ Vt[h]^T
  gemm128<true, false><<<dim3(32, 4, 2), 256, 0, stream>>>(
      S, NV_TOK, (long)NT_TOK * NV_TOK, Vt, NV_TOK, (long)HD * NV_TOK, nullptr,
      att_bf, EMBED, HD, NV_TOK);

  gemm128<false, true><<<dim3(32, 8, 1), 256, 0, stream>>>(
      att_bf, EMBED, 0, Wo_bf, EMBED, 0, bo, Ob, EMBED, 0, EMBED);
  ln_kernel<<<NT_TOK, 256, 0, stream>>>(Ob, nullptr, ln2_g, ln2_b, o2f, o2_bf);
  gemm128<false, true><<<dim3(32, 8, 1), 256, 0, stream>>>(
      o2_bf, EMBED, 0, Wl_bf, EMBED, 0, bl, lin, EMBED, 0, EMBED);
  ln_kernel<<<NT_TOK, 256, 0, stream>>>(o2f, lin, ln3_g, ln3_b, out, nullptr);
}

// Round 4
// 171.353 us; speedup vs baseline: 3.8346x; 1.0283x over previous
//
#include <hip/hip_runtime.h>
#include <math.h>

#define EMBED 512
#define HD 256
#define FR 12
#define NV 64
#define NT_TOK 4096
#define NV_TOK 768

// s_waitcnt immediates (gfx9 encoding): vmcnt[3:0]|vmcnt[5:4]@14, expcnt[6:4], lgkmcnt[11:8]
#define WAIT_VM6 0x0F76   // vmcnt<=6, lgkm/exp don't-care
#define WAIT_VM0 0x0F70   // vmcnt<=0

typedef __attribute__((ext_vector_type(8))) short short8;
typedef __attribute__((ext_vector_type(4))) float f32x4;

__device__ __forceinline__ unsigned int f2bf(float f) {
  unsigned int u = __float_as_uint(f);
  u += 0x7FFFu + ((u >> 16) & 1u);   // RNE
  return u >> 16;
}
__device__ __forceinline__ float bf2f(unsigned int h) {
  return __uint_as_float(h << 16);
}
__device__ __forceinline__ void async_cp16(void* lds, const void* g) {
  __builtin_amdgcn_global_load_lds(
      (const __attribute__((address_space(1))) void*)g,
      (__attribute__((address_space(3))) void*)lds, 16, 0, 0);
}

// ================= GEMM core: 128x64 C-tile, BK=64, double-buffered ========
// A: [M][lda] bf16 rows-m k-contig; B: [N][ldb] bf16 rows-n k-contig.
// LDS XOR-swizzled (chunk ^ row&7). Pipelined: prefetch tile k+1 with
// global_load_lds, raw s_barrier + s_waitcnt vmcnt(6) so the prefetch stays
// in flight across the barrier (no vmcnt(0) drain except last tile).
// As: 2 x 8192 elems (32KB), Bs: 2 x 4096 elems (16KB).
__device__ __forceinline__ void gemm_core(
    const unsigned short* __restrict__ Ab, int lda,
    const unsigned short* __restrict__ Bb, int ldb,
    int m0, int n0, int K,
    unsigned short* __restrict__ As, unsigned short* __restrict__ Bs,
    f32x4 acc[4][2]) {
  int tid = threadIdx.x;
  int w = tid >> 6, lane = tid & 63;
  int lr = lane & 15, quad = lane >> 4;
  int wm = (w >> 1) * 64, wn = (w & 1) * 32;
  int rowA[4], cgA[4], rowB[2], cgB[2];
  #pragma unroll
  for (int i = 0; i < 4; ++i) {
    int s = tid + i * 256;
    rowA[i] = s >> 3; cgA[i] = (s & 7) ^ (rowA[i] & 7);
  }
  #pragma unroll
  for (int i = 0; i < 2; ++i) {
    int s = tid + i * 256;
    rowB[i] = s >> 3; cgB[i] = (s & 7) ^ (rowB[i] & 7);
  }
  int nk = K >> 6;
  // prologue: tile 0 -> buffer 0 (6 issues per wave-lane-set)
  #pragma unroll
  for (int i = 0; i < 4; ++i)
    async_cp16(&As[(tid + i * 256) * 8],
               Ab + (size_t)(m0 + rowA[i]) * lda + cgA[i] * 8);
  #pragma unroll
  for (int i = 0; i < 2; ++i)
    async_cp16(&Bs[(tid + i * 256) * 8],
               Bb + (size_t)(n0 + rowB[i]) * ldb + cgB[i] * 8);
  for (int k = 0; k < nk; ++k) {
    int cur = k & 1;
    // barrier 1: all waves done computing tile k-1 -> safe to overwrite
    // buffer (k+1)&1 == (k-1)&1
    __builtin_amdgcn_s_barrier();
    if (k + 1 < nk) {
      int nxt = cur ^ 1;
      int koff = (k + 1) << 6;
      #pragma unroll
      for (int i = 0; i < 4; ++i)
        async_cp16(&As[nxt * 8192 + (tid + i * 256) * 8],
                   Ab + (size_t)(m0 + rowA[i]) * lda + koff + cgA[i] * 8);
      #pragma unroll
      for (int i = 0; i < 2; ++i)
        async_cp16(&Bs[nxt * 4096 + (tid + i * 256) * 8],
                   Bb + (size_t)(n0 + rowB[i]) * ldb + koff + cgB[i] * 8);
      __builtin_amdgcn_s_waitcnt(WAIT_VM6);  // tile k landed; k+1 in flight
    } else {
      __builtin_amdgcn_s_waitcnt(WAIT_VM0);
    }
    __builtin_amdgcn_s_barrier();  // tile k visible to all waves
    const unsigned short* Ac = As + cur * 8192;
    const unsigned short* Bc = Bs + cur * 4096;
    #pragma unroll
    for (int kk = 0; kk < 2; ++kk) {
      int sw = ((kk * 4 + quad) ^ (lr & 7)) * 8;
      short8 b0 = *(const short8*)&Bc[(wn + lr) * 64 + sw];
      short8 b1 = *(const short8*)&Bc[(wn + 16 + lr) * 64 + sw];
      #pragma unroll
      for (int i = 0; i < 4; ++i) {
        short8 a = *(const short8*)&Ac[(wm + i * 16 + lr) * 64 + sw];
        acc[i][0] = __builtin_amdgcn_mfma_f32_16x16x32_bf16(a, b0, acc[i][0], 0, 0, 0);
        acc[i][1] = __builtin_amdgcn_mfma_f32_16x16x32_bf16(a, b1, acc[i][1], 0, 0, 0);
      }
    }
  }
}

// ================= generic GEMM kernel (S / PV / O / L) ====================
template <bool OUT_BF, bool BIAS>
__global__ __launch_bounds__(256) void gemm128(
    const unsigned short* __restrict__ A, int lda, long AzS,
    const unsigned short* __restrict__ B, int ldb, long BzS,
    const float* __restrict__ bias, void* __restrict__ Cv, int ldc, long CzS,
    int K) {
  __shared__ __align__(16) unsigned short As[2 * 128 * 64];
  __shared__ __align__(16) unsigned short Bs[2 * 64 * 64];
  f32x4 acc[4][2] = {};
  const unsigned short* Ab = A + (size_t)blockIdx.z * AzS;
  const unsigned short* Bb = B + (size_t)blockIdx.z * BzS;
  int m0 = blockIdx.x * 128, n0 = blockIdx.y * 64;
  gemm_core(Ab, lda, Bb, ldb, m0, n0, K, As, Bs, acc);
  int w = threadIdx.x >> 6, lane = threadIdx.x & 63;
  int lr = lane & 15, quad = lane >> 4;
  int wm = (w >> 1) * 64, wn = (w & 1) * 32;
  long cz = (long)blockIdx.z * CzS;
  #pragma unroll
  for (int j = 0; j < 2; ++j) {
    int col = n0 + wn + j * 16 + lr;
    float bv = BIAS ? bias[col] : 0.0f;
    #pragma unroll
    for (int i = 0; i < 4; ++i) {
      int rbase = m0 + wm + i * 16 + quad * 4;
      #pragma unroll
      for (int r = 0; r < 4; ++r) {
        float v = acc[i][j][r] + bv;
        if (OUT_BF)
          ((unsigned short*)Cv)[cz + (size_t)(rbase + r) * ldc + col] =
              (unsigned short)f2bf(v);
        else
          ((float*)Cv)[cz + (size_t)(rbase + r) * ldc + col] = v;
      }
    }
  }
}

// ================= fused Q/K/V projection (+ direct-transposed V) ==========
__global__ __launch_bounds__(256) void qkv_kernel(
    const unsigned short* __restrict__ tn, const unsigned short* __restrict__ vn,
    const unsigned short* __restrict__ Wq, const unsigned short* __restrict__ Wk,
    const unsigned short* __restrict__ Wv,
    const float* __restrict__ bq, const float* __restrict__ bk,
    const float* __restrict__ bv,
    unsigned short* __restrict__ Q, unsigned short* __restrict__ Kout,
    unsigned short* __restrict__ Vt) {
  __shared__ __align__(16) unsigned short As[2 * 128 * 64];
  __shared__ __align__(16) unsigned short Bs[2 * 64 * 64];
  int bid = blockIdx.x;
  const unsigned short *Ap, *Bp;
  const float* bias;
  unsigned short* outp = nullptr;
  int m0, n0, mode;
  if (bid < 256) {            // Q: 32x8 blocks
    Ap = tn; Bp = Wq; bias = bq; outp = Q;
    m0 = (bid >> 3) * 128; n0 = (bid & 7) * 64; mode = 0;
  } else if (bid < 304) {     // K: 6x8 blocks
    int i = bid - 256;
    Ap = vn; Bp = Wk; bias = bk; outp = Kout;
    m0 = (i >> 3) * 128; n0 = (i & 7) * 64; mode = 0;
  } else {                    // V -> Vt: 6x8 blocks
    int i = bid - 304;
    Ap = vn; Bp = Wv; bias = bv;
    m0 = (i >> 3) * 128; n0 = (i & 7) * 64; mode = 1;
  }
  f32x4 acc[4][2] = {};
  gemm_core(Ap, EMBED, Bp, EMBED, m0, n0, EMBED, As, Bs, acc);
  int w = threadIdx.x >> 6, lane = threadIdx.x & 63;
  int lr = lane & 15, quad = lane >> 4;
  int wm = (w >> 1) * 64, wn = (w & 1) * 32;
  #pragma unroll
  for (int j = 0; j < 2; ++j) {
    int col = n0 + wn + j * 16 + lr;
    float bvv = bias[col];
    #pragma unroll
    for (int i = 0; i < 4; ++i) {
      int rbase = m0 + wm + i * 16 + quad * 4;
      if (mode == 0) {
        #pragma unroll
        for (int r = 0; r < 4; ++r)
          outp[(size_t)(rbase + r) * EMBED + col] =
              (unsigned short)f2bf(acc[i][j][r] + bvv);
      } else {
        ushort4 pk;
        pk.x = (unsigned short)f2bf(acc[i][j][0] + bvv);
        pk.y = (unsigned short)f2bf(acc[i][j][1] + bvv);
        pk.z = (unsigned short)f2bf(acc[i][j][2] + bvv);
        pk.w = (unsigned short)f2bf(acc[i][j][3] + bvv);
        *(ushort4*)&Vt[(size_t)col * NV_TOK + rbase] = pk;  // Vt[d][t]
      }
    }
  }
}

// ================= LayerNorm row helper ====================================
__device__ __forceinline__ void ln_row(
    const float* __restrict__ xr, const float* __restrict__ rr,
    const float* __restrict__ g, const float* __restrict__ b,
    float* __restrict__ outf, unsigned short* __restrict__ outb) {
  int t = threadIdx.x;
  float v0 = xr[t], v1 = xr[t + 256];
  if (rr != nullptr) { v0 += rr[t]; v1 += rr[t + 256]; }
  float s = v0 + v1;
  float s2 = v0 * v0 + v1 * v1;
  #pragma unroll
  for (int off = 32; off > 0; off >>= 1) {
    s += __shfl_down(s, off, 64);
    s2 += __shfl_down(s2, off, 64);
  }
  __shared__ float ss[4], ss2[4];
  __shared__ float mean_s, rstd_s;
  int wid = t >> 6;
  if ((t & 63) == 0) { ss[wid] = s; ss2[wid] = s2; }
  __syncthreads();
  if (t == 0) {
    float a = ss[0] + ss[1] + ss[2] + ss[3];
    float a2 = ss2[0] + ss2[1] + ss2[2] + ss2[3];
    float mean = a * (1.0f / EMBED);
    float var = a2 * (1.0f / EMBED) - mean * mean;
    mean_s = mean;
    rstd_s = rsqrtf(var + 1e-5f);
  }
  __syncthreads();
  float mean = mean_s, rstd = rstd_s;
  float y0 = (v0 - mean) * rstd * g[t] + b[t];
  float y1 = (v1 - mean) * rstd * g[t + 256] + b[t + 256];
  if (outf != nullptr) { outf[t] = y0; outf[t + 256] = y1; }
  if (outb != nullptr) {
    outb[t] = (unsigned short)f2bf(y0);
    outb[t + 256] = (unsigned short)f2bf(y1);
  }
}

__global__ __launch_bounds__(256) void ln_kernel(
    const float* __restrict__ x, const float* __restrict__ res,
    const float* __restrict__ g, const float* __restrict__ b,
    float* __restrict__ outf, unsigned short* __restrict__ outb) {
  size_t row = blockIdx.x;
  ln_row(x + row * EMBED, res ? res + row * EMBED : nullptr, g, b,
         outf ? outf + row * EMBED : nullptr,
         outb ? outb + row * EMBED : nullptr);
}

// ========= prep: weight fp32->bf16 (5x512x512) + LN1 on text & video =======
__global__ __launch_bounds__(256) void prep_kernel(
    const float* __restrict__ text, const float* __restrict__ video,
    const float* __restrict__ g, const float* __restrict__ b,
    const float* __restrict__ Wq, const float* __restrict__ Wk,
    const float* __restrict__ Wv, const float* __restrict__ Wo,
    const float* __restrict__ Wl, unsigned short* __restrict__ Wbf,
    unsigned short* __restrict__ tn, unsigned short* __restrict__ vn) {
  int bid = blockIdx.x;
  if (bid < 1280) {  // weight convert: one float4 per thread
    int i = bid * 256 + threadIdx.x;
    const float* srcs[5] = {Wq, Wk, Wv, Wo, Wl};
    const float* src = srcs[i >> 16];
    float4 v = ((const float4*)src)[i & 65535];
    uint2 o;
    o.x = f2bf(v.x) | (f2bf(v.y) << 16);
    o.y = f2bf(v.z) | (f2bf(v.w) << 16);
    ((uint2*)Wbf)[i] = o;
    return;
  }
  if (bid < 1280 + NT_TOK) {
    size_t row = bid - 1280;
    ln_row(text + row * EMBED, nullptr, g, b, nullptr, tn + row * EMBED);
  } else {
    size_t row = bid - (1280 + NT_TOK);
    ln_row(video + row * EMBED, nullptr, g, b, nullptr, vn + row * EMBED);
  }
}

// ========= in-place group softmax over 12 frames (folds 1/16 and 1/64) =====
// LDS-staged so global traffic is fully coalesced (uint2 stride-256 loads).
__global__ __launch_bounds__(256) void softmax12_kernel(unsigned short* __restrict__ S) {
  __shared__ uint2 buf[768];   // 256 groups x 12 bf16 = 768 uint2
  int t = threadIdx.x;
  uint2* g = (uint2*)S + (size_t)blockIdx.x * 768;
  #pragma unroll
  for (int i = 0; i < 3; ++i) buf[t + i * 256] = g[t + i * 256];
  __syncthreads();
  uint2 u0 = buf[t * 3], u1 = buf[t * 3 + 1], u2 = buf[t * 3 + 2];
  float v[12];
  v[0] = bf2f(u0.x & 0xffff); v[1] = bf2f(u0.x >> 16);
  v[2] = bf2f(u0.y & 0xffff); v[3] = bf2f(u0.y >> 16);
  v[4] = bf2f(u1.x & 0xffff); v[5] = bf2f(u1.x >> 16);
  v[6] = bf2f(u1.y & 0xffff); v[7] = bf2f(u1.y >> 16);
  v[8] = bf2f(u2.x & 0xffff); v[9] = bf2f(u2.x >> 16);
  v[10] = bf2f(u2.y & 0xffff); v[11] = bf2f(u2.y >> 16);
  float m = -1e30f;
  #pragma unroll
  for (int f = 0; f < FR; ++f) { v[f] *= 0.0625f; m = fmaxf(m, v[f]); }
  float s = 0.f;
  #pragma unroll
  for (int f = 0; f < FR; ++f) { v[f] = __expf(v[f] - m); s += v[f]; }
  float inv = (1.0f / NV) / s;
  unsigned int w[12];
  #pragma unroll
  for (int f = 0; f < FR; ++f) w[f] = f2bf(v[f] * inv);
  uint2 o0, o1, o2;
  o0.x = w[0] | (w[1] << 16);  o0.y = w[2] | (w[3] << 16);
  o1.x = w[4] | (w[5] << 16);  o1.y = w[6] | (w[7] << 16);
  o2.x = w[8] | (w[9] << 16);  o2.y = w[10] | (w[11] << 16);
  buf[t * 3] = o0; buf[t * 3 + 1] = o1; buf[t * 3 + 2] = o2;
  __syncthreads();
  #pragma unroll
  for (int i = 0; i < 3; ++i) g[t + i * 256] = buf[t + i * 256];
}

// ================= Launch ==================================================
extern "C" void kernel_launch(void* const* d_in, const int* in_sizes, int n_in,
                              void* d_out, int out_size, void* d_ws, size_t ws_size,
                              hipStream_t stream) {
  (void)in_sizes; (void)n_in; (void)out_size; (void)ws_size;
  const float* text  = (const float*)d_in[0];
  const float* video = (const float*)d_in[1];
  const float* ln1_g = (const float*)d_in[2];
  const float* ln1_b = (const float*)d_in[3];
  const float* Wq = (const float*)d_in[4];
  const float* bq = (const float*)d_in[5];
  const float* Wk = (const float*)d_in[6];
  const float* bk = (const float*)d_in[7];
  const float* Wv = (const float*)d_in[8];
  const float* bv = (const float*)d_in[9];
  const float* Wo = (const float*)d_in[10];
  const float* bo = (const float*)d_in[11];
  const float* Wl = (const float*)d_in[12];
  const float* bl = (const float*)d_in[13];
  const float* ln2_g = (const float*)d_in[14];
  const float* ln2_b = (const float*)d_in[15];
  const float* ln3_g = (const float*)d_in[16];
  const float* ln3_b = (const float*)d_in[17];
  float* out = (float*)d_out;

  // ---- workspace layout (29.36 MB; aliased phase-by-phase) ----
  char* base = (char*)d_ws;
  unsigned short* Wbf   = (unsigned short*)base;              // 5 x 262144 bf16
  unsigned short* Wq_bf = Wbf + 0 * 262144;
  unsigned short* Wk_bf = Wbf + 1 * 262144;
  unsigned short* Wv_bf = Wbf + 2 * 262144;
  unsigned short* Wo_bf = Wbf + 3 * 262144;
  unsigned short* Wl_bf = Wbf + 4 * 262144;
  unsigned short* Vt    = (unsigned short*)(base + 2621440);  // [512][768]
  char* big = base + 3407872;
  unsigned short* Q_bf   = (unsigned short*)(big + 0);         // 4096x512
  unsigned short* K_bf   = (unsigned short*)(big + 4194304);   // 768x512
  unsigned short* S      = (unsigned short*)(big + 4980736);   // 2x4096x768
  unsigned short* tn_bf  = (unsigned short*)(big + 17563648);  // 4096x512
  unsigned short* vn_bf  = (unsigned short*)(big + 21757952);  // 768x512
  unsigned short* att_bf = (unsigned short*)(big + 17563648);  // over tn (dead)
  float*          Ob     = (float*)(big + 4980736);            // over S (dead)
  float*          o2f    = (float*)(big + 13369344);           // over S tail
  unsigned short* o2_bf  = (unsigned short*)(big + 21757952);  // over vn (dead)
  float*          lin    = (float*)(big + 0);                  // over Q/K (dead)

  prep_kernel<<<1280 + NT_TOK + NV_TOK, 256, 0, stream>>>(
      text, video, ln1_g, ln1_b, Wq, Wk, Wv, Wo, Wl, Wbf, tn_bf, vn_bf);

  qkv_kernel<<<352, 256, 0, stream>>>(tn_bf, vn_bf, Wq_bf, Wk_bf, Wv_bf,
                                      bq, bk, bv, Q_bf, K_bf, Vt);

  // S[h] = Q_h @ K_h^T  (logits; scale folded into softmax)
  gemm128<true, false><<<dim3(32, 12, 2), 256, 0, stream>>>(
      Q_bf, EMBED, HD, K_bf, EMBED, HD, nullptr, S, NV_TOK,
      (long)NT_TOK * NV_TOK, HD);
  softmax12_kernel<<<2048, 256, 0, stream>>>(S);
  // att[:, h*256+d] = P[h] @ Vt[h]^T
  gemm128<true, false><<<dim3(32, 4, 2), 256, 0, stream>>>(
      S, NV_TOK, (long)NT_TOK * NV_TOK, Vt, NV_TOK, (long)HD * NV_TOK, nullptr,
      att_bf, EMBED, HD, NV_TOK);

  gemm128<false, true><<<dim3(32, 8, 1), 256, 0, stream>>>(
      att_bf, EMBED, 0, Wo_bf, EMBED, 0, bo, Ob, EMBED, 0, EMBED);
  ln_kernel<<<NT_TOK, 256, 0, stream>>>(Ob, nullptr, ln2_g, ln2_b, o2f, o2_bf);
  gemm128<false, true><<<dim3(32, 8, 1), 256, 0, stream>>>(
      o2_bf, EMBED, 0, Wl_bf, EMBED, 0, bl, lin, EMBED, 0, EMBED);
  ln_kernel<<<NT_TOK, 256, 0, stream>>>(o2f, lin, ln3_g, ln3_b, out, nullptr);
}